// Round 3
// baseline (11792.842 us; speedup 1.0000x reference)
//
#include <hip/hip_runtime.h>
#include <math.h>

#define NCODES 16384
#define DIM    256
#define CH     256
#define HW     1024
#define MTOT   16384
#define OUT_ELEMS 4194304

#define BM 128          // rows per block
#define CT 256          // col tile
#define BK 8            // k chunk
#define NHALF 8192      // cols per block (N split in 2)

// separately-rounded f32 multiply (blocks FMA contraction: numpy computes
// the product array first, then pairwise-sums it)
__device__ __forceinline__ float mulr(float a, float b) {
    float p = a * b;
    asm volatile("" : "+v"(p));
    return p;
}

// ---------------- kernel 1: codebook row norms, numpy pairwise order ----------------
__global__ __launch_bounds__(256) void k_cnorm(const float* __restrict__ cb,
                                               float* __restrict__ cnorm) {
    int row = blockIdx.x * 256 + threadIdx.x;
    const float* cp = cb + (size_t)row * DIM;
    float r0[8], r1[8];
    #pragma unroll
    for (int j = 0; j < 8; ++j) {
        float v0 = cp[j], v1 = cp[128 + j];
        r0[j] = mulr(v0, v0);
        r1[j] = mulr(v1, v1);
    }
    for (int i = 8; i < 128; i += 8) {
        #pragma unroll
        for (int j = 0; j < 8; ++j) {
            float v0 = cp[i + j], v1 = cp[128 + i + j];
            r0[j] += mulr(v0, v0);
            r1[j] += mulr(v1, v1);
        }
    }
    float s0 = ((r0[0] + r0[1]) + (r0[2] + r0[3])) + ((r0[4] + r0[5]) + (r0[6] + r0[7]));
    float s1 = ((r1[0] + r1[1]) + (r1[2] + r1[3])) + ((r1[4] + r1[5]) + (r1[6] + r1[7]));
    cnorm[row] = s0 + s1;
}

// ---------------- kernel 1b: z row norms (strided layout), same numpy order ----------
__global__ __launch_bounds__(256) void k_anorm(const float* __restrict__ z,
                                               float* __restrict__ anorm) {
    int m = blockIdx.x * 256 + threadIdx.x;
    int b = m / HW, hw = m % HW;
    const float* zp = z + (size_t)b * (CH * HW) + hw;
    float r0[8], r1[8];
    #pragma unroll
    for (int j = 0; j < 8; ++j) {
        float v0 = zp[(size_t)j * HW];
        float v1 = zp[(size_t)(128 + j) * HW];
        r0[j] = mulr(v0, v0);
        r1[j] = mulr(v1, v1);
    }
    for (int i = 8; i < 128; i += 8) {
        #pragma unroll
        for (int j = 0; j < 8; ++j) {
            float v0 = zp[(size_t)(i + j) * HW];
            float v1 = zp[(size_t)(128 + i + j) * HW];
            r0[j] += mulr(v0, v0);
            r1[j] += mulr(v1, v1);
        }
    }
    float s0 = ((r0[0] + r0[1]) + (r0[2] + r0[3])) + ((r0[4] + r0[5]) + (r0[6] + r0[7]));
    float s1 = ((r1[0] + r1[1]) + (r1[2] + r1[3])) + ((r1[4] + r1[5]) + (r1[6] + r1[7]));
    anorm[m] = s0 + s1;
}

// ---------------- kernel 2: GEMM (sequential-k f32 FMA, BLAS order) + argmin --------
// Each block: BM=128 rows x one N-half (8192 cols). TM=8 x TN=16 per thread.
// d(m,n) = fl( fl(A_m + B_n) - 2*P_mn ); per-half lexicographic (d,n) top-1.
__global__ __launch_bounds__(256, 2) void k_argmin(const float* __restrict__ z,
                                                   const float* __restrict__ cb,
                                                   const float* __restrict__ cnorm,
                                                   const float* __restrict__ anorm,
                                                   float* __restrict__ pv,
                                                   int* __restrict__ pi) {
    __shared__ float lds_a[2][BK][BM];   // 8 KB
    __shared__ float lds_b[2][BK][CT];   // 16 KB

    const int t  = threadIdx.x;
    const int tx = t & 15;               // 16 col-groups
    const int ty = t >> 4;               // 16 row-groups (TM=8 rows each)
    const int mb   = (int)(blockIdx.x >> 1) * BM;
    const int half = (int)(blockIdx.x & 1);
    const int colbase = half * NHALF;
    const int zb  = mb / HW;             // 128 | 1024: no batch straddle
    const int hw0 = mb % HW;
    const float* zbase = z + (size_t)zb * (CH * HW) + hw0;

    // staging roles
    const int sa_d = t >> 5;             // 0..7
    const int sa_m = (t & 31) * 4;       // 0..124

    float Am[8];
    #pragma unroll
    for (int i = 0; i < 8; ++i) Am[i] = anorm[mb + ty * 8 + i];

    float bv[8];
    int   bi[8];
    #pragma unroll
    for (int i = 0; i < 8; ++i) { bv[i] = INFINITY; bi[i] = 0x7fffffff; }

    for (int nt = 0; nt < NHALF / CT; ++nt) {
        const int n0 = colbase + nt * CT;
        const float* crow = cb + (size_t)(n0 + t) * DIM;

        float acc[8][16];
        #pragma unroll
        for (int i = 0; i < 8; ++i)
            #pragma unroll
            for (int j = 0; j < 16; ++j) acc[i][j] = 0.f;

        // prologue: chunk 0 into buf 0
        float4 a0 = *reinterpret_cast<const float4*>(zbase + (size_t)sa_d * HW + sa_m);
        float4 u0 = *reinterpret_cast<const float4*>(crow + 0);
        float4 u1 = *reinterpret_cast<const float4*>(crow + 4);
        __syncthreads();  // previous tile's buffer reads complete
        *reinterpret_cast<float4*>(&lds_a[0][sa_d][sa_m]) = a0;
        lds_b[0][0][t] = u0.x; lds_b[0][1][t] = u0.y; lds_b[0][2][t] = u0.z; lds_b[0][3][t] = u0.w;
        lds_b[0][4][t] = u1.x; lds_b[0][5][t] = u1.y; lds_b[0][6][t] = u1.z; lds_b[0][7][t] = u1.w;

        for (int kc = 0; kc < DIM / BK; ++kc) {
            const int cur = kc & 1;
            __syncthreads();  // buf[cur] visible; buf[cur^1] free to overwrite

            float4 na, nb0, nb1;
            if (kc < DIM / BK - 1) {
                na  = *reinterpret_cast<const float4*>(zbase + (size_t)((kc + 1) * BK + sa_d) * HW + sa_m);
                nb0 = *reinterpret_cast<const float4*>(crow + (kc + 1) * BK);
                nb1 = *reinterpret_cast<const float4*>(crow + (kc + 1) * BK + 4);
            }

            #pragma unroll
            for (int kk = 0; kk < BK; ++kk) {
                float af[8];
                *reinterpret_cast<float4*>(&af[0]) = *reinterpret_cast<const float4*>(&lds_a[cur][kk][ty * 8]);
                *reinterpret_cast<float4*>(&af[4]) = *reinterpret_cast<const float4*>(&lds_a[cur][kk][ty * 8 + 4]);
                float bf[16];
                *reinterpret_cast<float4*>(&bf[0])  = *reinterpret_cast<const float4*>(&lds_b[cur][kk][tx * 4]);
                *reinterpret_cast<float4*>(&bf[4])  = *reinterpret_cast<const float4*>(&lds_b[cur][kk][64 + tx * 4]);
                *reinterpret_cast<float4*>(&bf[8])  = *reinterpret_cast<const float4*>(&lds_b[cur][kk][128 + tx * 4]);
                *reinterpret_cast<float4*>(&bf[12]) = *reinterpret_cast<const float4*>(&lds_b[cur][kk][192 + tx * 4]);
                #pragma unroll
                for (int i = 0; i < 8; ++i)
                    #pragma unroll
                    for (int j = 0; j < 16; ++j)
                        acc[i][j] = fmaf(af[i], bf[j], acc[i][j]);  // sequential k: matches sgemm
            }

            if (kc < DIM / BK - 1) {
                const int nb = cur ^ 1;
                *reinterpret_cast<float4*>(&lds_a[nb][sa_d][sa_m]) = na;
                lds_b[nb][0][t] = nb0.x; lds_b[nb][1][t] = nb0.y; lds_b[nb][2][t] = nb0.z; lds_b[nb][3][t] = nb0.w;
                lds_b[nb][4][t] = nb1.x; lds_b[nb][5][t] = nb1.y; lds_b[nb][6][t] = nb1.z; lds_b[nb][7][t] = nb1.w;
            }
        }

        // epilogue: d = fl(fl(Am+Bn) - 2*P); lexicographic (d, n) running min
        float cnv[16];
        #pragma unroll
        for (int jb = 0; jb < 4; ++jb) {
            float4 c4 = *reinterpret_cast<const float4*>(cnorm + n0 + jb * 64 + tx * 4);
            cnv[jb * 4 + 0] = c4.x; cnv[jb * 4 + 1] = c4.y;
            cnv[jb * 4 + 2] = c4.z; cnv[jb * 4 + 3] = c4.w;
        }
        #pragma unroll
        for (int i = 0; i < 8; ++i)
            #pragma unroll
            for (int jb = 0; jb < 4; ++jb)
                #pragma unroll
                for (int jj = 0; jj < 4; ++jj) {
                    float t1 = Am[i] + cnv[jb * 4 + jj];
                    float dd = t1 - 2.0f * acc[i][jb * 4 + jj];
                    int n = n0 + jb * 64 + tx * 4 + jj;
                    if (dd < bv[i] || (dd == bv[i] && n < bi[i])) { bv[i] = dd; bi[i] = n; }
                }
    }

    // reduce across the 16 tx lanes (lane bits 0..3: stays within wave & ty group)
    #pragma unroll
    for (int i = 0; i < 8; ++i) {
        #pragma unroll
        for (int o = 1; o < 16; o <<= 1) {
            float ov = __shfl_xor(bv[i], o, 64);
            int   oi = __shfl_xor(bi[i], o, 64);
            if (ov < bv[i] || (ov == bv[i] && oi < bi[i])) { bv[i] = ov; bi[i] = oi; }
        }
        if (tx == 0) {
            int row = mb + ty * 8 + i;
            pv[half * MTOT + row] = bv[i];
            pi[half * MTOT + row] = bi[i];
        }
    }
}

// ---------------- kernel 2b: combine the two N-halves ----------------
__global__ __launch_bounds__(256) void k_combine(const float* __restrict__ pv,
                                                 const int* __restrict__ pi,
                                                 int* __restrict__ idxi,
                                                 float* __restrict__ idxf) {
    int m = blockIdx.x * 256 + threadIdx.x;
    float v0 = pv[m], v1 = pv[MTOT + m];
    int   i0 = pi[m], i1 = pi[MTOT + m];
    int best = (v1 < v0 || (v1 == v0 && i1 < i0)) ? i1 : i0;
    idxi[m] = best;
    idxf[m] = (float)best;
}

// ---------------- kernel 3: gather z_q, write out, accumulate loss ----------------
__global__ __launch_bounds__(256) void k_gather(const float* __restrict__ z,
                                                const float* __restrict__ cb,
                                                const int* __restrict__ idx,
                                                float* __restrict__ out,
                                                double* __restrict__ lacc) {
    int t = threadIdx.x;
    int hwi = t & 63, cg = t >> 6;
    int m = blockIdx.x * 64 + hwi;
    int b = m / HW, hw = m % HW;
    const float* erow = cb + (size_t)idx[m] * DIM;
    size_t zoff = (size_t)b * (CH * HW) + hw;
    double ls = 0.0;
    #pragma unroll 4
    for (int cc = 0; cc < 64; ++cc) {
        int c = cg * 64 + cc;
        float e  = erow[c];
        float zv = z[zoff + (size_t)c * HW];
        out[zoff + (size_t)c * HW] = e;
        float d = e - zv;
        ls += (double)d * (double)d;
    }
    #pragma unroll
    for (int o = 32; o; o >>= 1) ls += __shfl_xor(ls, o, 64);
    __shared__ double wsum[4];
    if ((t & 63) == 0) wsum[t >> 6] = ls;
    __syncthreads();
    if (t == 0) atomicAdd(lacc, wsum[0] + wsum[1] + wsum[2] + wsum[3]);
}

__global__ void k_final(const double* __restrict__ lacc, float* __restrict__ loss) {
    *loss = (float)(*lacc * (1.25 / (double)OUT_ELEMS));
}

extern "C" void kernel_launch(void* const* d_in, const int* in_sizes, int n_in,
                              void* d_out, int out_size, void* d_ws, size_t ws_size,
                              hipStream_t stream) {
    const float* z  = (const float*)d_in[0];
    const float* cb = (const float*)d_in[1];
    float* out      = (float*)d_out;
    float* loss_out = out + OUT_ELEMS;
    float* idxf     = out + OUT_ELEMS + 1;

    float*  cnorm = (float*)d_ws;                                  // 64 KB
    float*  anorm = (float*)((char*)d_ws + 65536);                 // 64 KB
    int*    idxi  = (int*)((char*)d_ws + 131072);                  // 64 KB
    float*  pv    = (float*)((char*)d_ws + 196608);                // 128 KB
    int*    pi    = (int*)((char*)d_ws + 327680);                  // 128 KB
    double* lacc  = (double*)((char*)d_ws + 458752);               // 8 B

    hipMemsetAsync(lacc, 0, sizeof(double), stream);

    k_cnorm  <<<NCODES / 256,    256, 0, stream>>>(cb, cnorm);
    k_anorm  <<<MTOT / 256,      256, 0, stream>>>(z, anorm);
    k_argmin <<<(MTOT / BM) * 2, 256, 0, stream>>>(z, cb, cnorm, anorm, pv, pi);
    k_combine<<<MTOT / 256,      256, 0, stream>>>(pv, pi, idxi, idxf);
    k_gather <<<MTOT / 64,       256, 0, stream>>>(z, cb, idxi, out, lacc);
    k_final  <<<1, 1, 0, stream>>>(lacc, loss_out);
}

// Round 4
// 9656.312 us; speedup vs baseline: 1.2213x; 1.2213x over previous
//
#include <hip/hip_runtime.h>
#include <math.h>

#define NCODES 16384
#define DIM    256
#define CH     256
#define HW     1024
#define MTOT   16384
#define OUT_ELEMS 4194304

#define BM 128          // rows per block
#define CT 256          // col tile
#define BK 8            // k chunk
#define NQ 4096         // cols per block (N split in 4 quarters)

// separately-rounded f32 multiply (blocks FMA contraction: numpy computes
// the product array first, then pairwise-sums it)
__device__ __forceinline__ float mulr(float a, float b) {
    float p = a * b;
    asm volatile("" : "+v"(p));
    return p;
}

// ---------------- kernel 1: codebook row norms, numpy pairwise order ----------------
__global__ __launch_bounds__(256) void k_cnorm(const float* __restrict__ cb,
                                               float* __restrict__ cnorm) {
    int row = blockIdx.x * 256 + threadIdx.x;
    const float* cp = cb + (size_t)row * DIM;
    float r0[8], r1[8];
    #pragma unroll
    for (int j = 0; j < 8; ++j) {
        float v0 = cp[j], v1 = cp[128 + j];
        r0[j] = mulr(v0, v0);
        r1[j] = mulr(v1, v1);
    }
    for (int i = 8; i < 128; i += 8) {
        #pragma unroll
        for (int j = 0; j < 8; ++j) {
            float v0 = cp[i + j], v1 = cp[128 + i + j];
            r0[j] += mulr(v0, v0);
            r1[j] += mulr(v1, v1);
        }
    }
    float s0 = ((r0[0] + r0[1]) + (r0[2] + r0[3])) + ((r0[4] + r0[5]) + (r0[6] + r0[7]));
    float s1 = ((r1[0] + r1[1]) + (r1[2] + r1[3])) + ((r1[4] + r1[5]) + (r1[6] + r1[7]));
    cnorm[row] = s0 + s1;
}

// ---------------- kernel 1b: z row norms (strided layout), same numpy order ----------
__global__ __launch_bounds__(256) void k_anorm(const float* __restrict__ z,
                                               float* __restrict__ anorm) {
    int m = blockIdx.x * 256 + threadIdx.x;
    int b = m / HW, hw = m % HW;
    const float* zp = z + (size_t)b * (CH * HW) + hw;
    float r0[8], r1[8];
    #pragma unroll
    for (int j = 0; j < 8; ++j) {
        float v0 = zp[(size_t)j * HW];
        float v1 = zp[(size_t)(128 + j) * HW];
        r0[j] = mulr(v0, v0);
        r1[j] = mulr(v1, v1);
    }
    for (int i = 8; i < 128; i += 8) {
        #pragma unroll
        for (int j = 0; j < 8; ++j) {
            float v0 = zp[(size_t)(i + j) * HW];
            float v1 = zp[(size_t)(128 + i + j) * HW];
            r0[j] += mulr(v0, v0);
            r1[j] += mulr(v1, v1);
        }
    }
    float s0 = ((r0[0] + r0[1]) + (r0[2] + r0[3])) + ((r0[4] + r0[5]) + (r0[6] + r0[7]));
    float s1 = ((r1[0] + r1[1]) + (r1[2] + r1[3])) + ((r1[4] + r1[5]) + (r1[6] + r1[7]));
    anorm[m] = s0 + s1;
}

// ---------------- kernel 2: GEMM (sequential-k f32 FMA, BLAS order) + argmin --------
// Each block: BM=128 rows x one N-quarter (4096 cols). TM=8 x TN=16 per thread.
// d(m,n) = fl( fl(A_m + B_n) - 2*P_mn ); per-quarter lexicographic (d,n) top-1.
__global__ __launch_bounds__(256)
__attribute__((amdgpu_waves_per_eu(2, 2)))
void k_argmin(const float* __restrict__ z,
              const float* __restrict__ cb,
              const float* __restrict__ cnorm,
              const float* __restrict__ anorm,
              float* __restrict__ pv,
              int* __restrict__ pi) {
    __shared__ float lds_a[2][BK][BM];   // 8 KB
    __shared__ float lds_b[2][BK][CT];   // 16 KB

    const int t  = threadIdx.x;
    const int tx = t & 15;               // 16 col-groups
    const int ty = t >> 4;               // 16 row-groups (TM=8 rows each)
    const int mb   = (int)(blockIdx.x >> 2) * BM;
    const int quar = (int)(blockIdx.x & 3);
    const int colbase = quar * NQ;
    const int zb  = mb / HW;             // 128 | 1024: no batch straddle
    const int hw0 = mb % HW;
    const float* zbase = z + (size_t)zb * (CH * HW) + hw0;

    // staging roles
    const int sa_d = t >> 5;             // 0..7
    const int sa_m = (t & 31) * 4;       // 0..124

    float Am[8];
    #pragma unroll
    for (int i = 0; i < 8; ++i) Am[i] = anorm[mb + ty * 8 + i];

    float bv[8];
    int   bi[8];
    #pragma unroll
    for (int i = 0; i < 8; ++i) { bv[i] = INFINITY; bi[i] = 0x7fffffff; }

    for (int nt = 0; nt < NQ / CT; ++nt) {
        const int n0 = colbase + nt * CT;
        const float* crow = cb + (size_t)(n0 + t) * DIM;

        float acc[8][16];
        #pragma unroll
        for (int i = 0; i < 8; ++i)
            #pragma unroll
            for (int j = 0; j < 16; ++j) acc[i][j] = 0.f;

        // prologue: chunk 0 into buf 0
        float4 a0 = *reinterpret_cast<const float4*>(zbase + (size_t)sa_d * HW + sa_m);
        float4 u0 = *reinterpret_cast<const float4*>(crow + 0);
        float4 u1 = *reinterpret_cast<const float4*>(crow + 4);
        __syncthreads();  // previous tile's buffer reads complete
        *reinterpret_cast<float4*>(&lds_a[0][sa_d][sa_m]) = a0;
        lds_b[0][0][t] = u0.x; lds_b[0][1][t] = u0.y; lds_b[0][2][t] = u0.z; lds_b[0][3][t] = u0.w;
        lds_b[0][4][t] = u1.x; lds_b[0][5][t] = u1.y; lds_b[0][6][t] = u1.z; lds_b[0][7][t] = u1.w;

        for (int kc = 0; kc < DIM / BK; ++kc) {
            const int cur = kc & 1;
            __syncthreads();  // buf[cur] visible; buf[cur^1] free to overwrite

            float4 na, nb0, nb1;
            if (kc < DIM / BK - 1) {
                na  = *reinterpret_cast<const float4*>(zbase + (size_t)((kc + 1) * BK + sa_d) * HW + sa_m);
                nb0 = *reinterpret_cast<const float4*>(crow + (kc + 1) * BK);
                nb1 = *reinterpret_cast<const float4*>(crow + (kc + 1) * BK + 4);
            }

            #pragma unroll
            for (int kk = 0; kk < BK; ++kk) {
                float af[8];
                *reinterpret_cast<float4*>(&af[0]) = *reinterpret_cast<const float4*>(&lds_a[cur][kk][ty * 8]);
                *reinterpret_cast<float4*>(&af[4]) = *reinterpret_cast<const float4*>(&lds_a[cur][kk][ty * 8 + 4]);
                float bf[16];
                *reinterpret_cast<float4*>(&bf[0])  = *reinterpret_cast<const float4*>(&lds_b[cur][kk][tx * 4]);
                *reinterpret_cast<float4*>(&bf[4])  = *reinterpret_cast<const float4*>(&lds_b[cur][kk][64 + tx * 4]);
                *reinterpret_cast<float4*>(&bf[8])  = *reinterpret_cast<const float4*>(&lds_b[cur][kk][128 + tx * 4]);
                *reinterpret_cast<float4*>(&bf[12]) = *reinterpret_cast<const float4*>(&lds_b[cur][kk][192 + tx * 4]);
                #pragma unroll
                for (int i = 0; i < 8; ++i)
                    #pragma unroll
                    for (int j = 0; j < 16; ++j)
                        acc[i][j] = fmaf(af[i], bf[j], acc[i][j]);  // sequential k: matches sgemm
            }

            if (kc < DIM / BK - 1) {
                const int nb = cur ^ 1;
                *reinterpret_cast<float4*>(&lds_a[nb][sa_d][sa_m]) = na;
                lds_b[nb][0][t] = nb0.x; lds_b[nb][1][t] = nb0.y; lds_b[nb][2][t] = nb0.z; lds_b[nb][3][t] = nb0.w;
                lds_b[nb][4][t] = nb1.x; lds_b[nb][5][t] = nb1.y; lds_b[nb][6][t] = nb1.z; lds_b[nb][7][t] = nb1.w;
            }
        }

        // epilogue: d = fl(fl(Am+Bn) - 2*P); lexicographic (d, n) running min
        float cnv[16];
        #pragma unroll
        for (int jb = 0; jb < 4; ++jb) {
            float4 c4 = *reinterpret_cast<const float4*>(cnorm + n0 + jb * 64 + tx * 4);
            cnv[jb * 4 + 0] = c4.x; cnv[jb * 4 + 1] = c4.y;
            cnv[jb * 4 + 2] = c4.z; cnv[jb * 4 + 3] = c4.w;
        }
        #pragma unroll
        for (int i = 0; i < 8; ++i)
            #pragma unroll
            for (int jb = 0; jb < 4; ++jb)
                #pragma unroll
                for (int jj = 0; jj < 4; ++jj) {
                    float t1 = Am[i] + cnv[jb * 4 + jj];
                    float dd = t1 - 2.0f * acc[i][jb * 4 + jj];
                    int n = n0 + jb * 64 + tx * 4 + jj;
                    if (dd < bv[i] || (dd == bv[i] && n < bi[i])) { bv[i] = dd; bi[i] = n; }
                }
    }

    // reduce across the 16 tx lanes (lane bits 0..3: stays within wave & ty group)
    #pragma unroll
    for (int i = 0; i < 8; ++i) {
        #pragma unroll
        for (int o = 1; o < 16; o <<= 1) {
            float ov = __shfl_xor(bv[i], o, 64);
            int   oi = __shfl_xor(bi[i], o, 64);
            if (ov < bv[i] || (ov == bv[i] && oi < bi[i])) { bv[i] = ov; bi[i] = oi; }
        }
        if (tx == 0) {
            int row = mb + ty * 8 + i;
            pv[quar * MTOT + row] = bv[i];
            pi[quar * MTOT + row] = bi[i];
        }
    }
}

// ---------------- kernel 2b: combine the four N-quarters ----------------
__global__ __launch_bounds__(256) void k_combine(const float* __restrict__ pv,
                                                 const int* __restrict__ pi,
                                                 int* __restrict__ idxi,
                                                 float* __restrict__ idxf) {
    int m = blockIdx.x * 256 + threadIdx.x;
    float v = pv[m];
    int   i = pi[m];
    #pragma unroll
    for (int q = 1; q < 4; ++q) {
        float vq = pv[q * MTOT + m];
        int   iq = pi[q * MTOT + m];
        if (vq < v || (vq == v && iq < i)) { v = vq; i = iq; }
    }
    idxi[m] = i;
    idxf[m] = (float)i;
}

// ---------------- kernel 3: gather z_q, write out, accumulate loss ----------------
__global__ __launch_bounds__(256) void k_gather(const float* __restrict__ z,
                                                const float* __restrict__ cb,
                                                const int* __restrict__ idx,
                                                float* __restrict__ out,
                                                double* __restrict__ lacc) {
    int t = threadIdx.x;
    int hwi = t & 63, cg = t >> 6;
    int m = blockIdx.x * 64 + hwi;
    int b = m / HW, hw = m % HW;
    const float* erow = cb + (size_t)idx[m] * DIM;
    size_t zoff = (size_t)b * (CH * HW) + hw;
    double ls = 0.0;
    #pragma unroll 4
    for (int cc = 0; cc < 64; ++cc) {
        int c = cg * 64 + cc;
        float e  = erow[c];
        float zv = z[zoff + (size_t)c * HW];
        out[zoff + (size_t)c * HW] = e;
        float d = e - zv;
        ls += (double)d * (double)d;
    }
    #pragma unroll
    for (int o = 32; o; o >>= 1) ls += __shfl_xor(ls, o, 64);
    __shared__ double wsum[4];
    if ((t & 63) == 0) wsum[t >> 6] = ls;
    __syncthreads();
    if (t == 0) atomicAdd(lacc, wsum[0] + wsum[1] + wsum[2] + wsum[3]);
}

__global__ void k_final(const double* __restrict__ lacc, float* __restrict__ loss) {
    *loss = (float)(*lacc * (1.25 / (double)OUT_ELEMS));
}

extern "C" void kernel_launch(void* const* d_in, const int* in_sizes, int n_in,
                              void* d_out, int out_size, void* d_ws, size_t ws_size,
                              hipStream_t stream) {
    const float* z  = (const float*)d_in[0];
    const float* cb = (const float*)d_in[1];
    float* out      = (float*)d_out;
    float* loss_out = out + OUT_ELEMS;
    float* idxf     = out + OUT_ELEMS + 1;

    float*  cnorm = (float*)d_ws;                                  // 64 KB
    float*  anorm = (float*)((char*)d_ws + 65536);                 // 64 KB
    int*    idxi  = (int*)((char*)d_ws + 131072);                  // 64 KB
    float*  pv    = (float*)((char*)d_ws + 196608);                // 256 KB
    int*    pi    = (int*)((char*)d_ws + 458752);                  // 256 KB
    double* lacc  = (double*)((char*)d_ws + 720896);               // 8 B

    hipMemsetAsync(lacc, 0, sizeof(double), stream);

    k_cnorm  <<<NCODES / 256,    256, 0, stream>>>(cb, cnorm);
    k_anorm  <<<MTOT / 256,      256, 0, stream>>>(z, anorm);
    k_argmin <<<(MTOT / BM) * 4, 256, 0, stream>>>(z, cb, cnorm, anorm, pv, pi);
    k_combine<<<MTOT / 256,      256, 0, stream>>>(pv, pi, idxi, idxf);
    k_gather <<<MTOT / 64,       256, 0, stream>>>(z, cb, idxi, out, lacc);
    k_final  <<<1, 1, 0, stream>>>(lacc, loss_out);
}

// Round 5
// 9075.093 us; speedup vs baseline: 1.2995x; 1.0640x over previous
//
#include <hip/hip_runtime.h>
#include <math.h>

#define NCODES 16384
#define DIM    256
#define CH     256
#define HW     1024
#define MTOT   16384
#define OUT_ELEMS 4194304

#define BM 128          // rows per block
#define CT 256          // col tile
#define BK 8            // k chunk
#define NQ 4096         // cols per block (N split in 4 quarters)

// separately-rounded f32 multiply (blocks FMA contraction: numpy computes
// the product array first, then pairwise-sums it)
__device__ __forceinline__ float mulr(float a, float b) {
    float p = a * b;
    asm volatile("" : "+v"(p));
    return p;
}

// ---------------- kernel 1: codebook row norms, numpy pairwise order ----------------
__global__ __launch_bounds__(256) void k_cnorm(const float* __restrict__ cb,
                                               float* __restrict__ cnorm) {
    int row = blockIdx.x * 256 + threadIdx.x;
    const float* cp = cb + (size_t)row * DIM;
    float r0[8], r1[8];
    #pragma unroll
    for (int j = 0; j < 8; ++j) {
        float v0 = cp[j], v1 = cp[128 + j];
        r0[j] = mulr(v0, v0);
        r1[j] = mulr(v1, v1);
    }
    for (int i = 8; i < 128; i += 8) {
        #pragma unroll
        for (int j = 0; j < 8; ++j) {
            float v0 = cp[i + j], v1 = cp[128 + i + j];
            r0[j] += mulr(v0, v0);
            r1[j] += mulr(v1, v1);
        }
    }
    float s0 = ((r0[0] + r0[1]) + (r0[2] + r0[3])) + ((r0[4] + r0[5]) + (r0[6] + r0[7]));
    float s1 = ((r1[0] + r1[1]) + (r1[2] + r1[3])) + ((r1[4] + r1[5]) + (r1[6] + r1[7]));
    cnorm[row] = s0 + s1;
}

// ---------------- kernel 1b: z row norms (strided layout), same numpy order ----------
__global__ __launch_bounds__(256) void k_anorm(const float* __restrict__ z,
                                               float* __restrict__ anorm) {
    int m = blockIdx.x * 256 + threadIdx.x;
    int b = m / HW, hw = m % HW;
    const float* zp = z + (size_t)b * (CH * HW) + hw;
    float r0[8], r1[8];
    #pragma unroll
    for (int j = 0; j < 8; ++j) {
        float v0 = zp[(size_t)j * HW];
        float v1 = zp[(size_t)(128 + j) * HW];
        r0[j] = mulr(v0, v0);
        r1[j] = mulr(v1, v1);
    }
    for (int i = 8; i < 128; i += 8) {
        #pragma unroll
        for (int j = 0; j < 8; ++j) {
            float v0 = zp[(size_t)(i + j) * HW];
            float v1 = zp[(size_t)(128 + i + j) * HW];
            r0[j] += mulr(v0, v0);
            r1[j] += mulr(v1, v1);
        }
    }
    float s0 = ((r0[0] + r0[1]) + (r0[2] + r0[3])) + ((r0[4] + r0[5]) + (r0[6] + r0[7]));
    float s1 = ((r1[0] + r1[1]) + (r1[2] + r1[3])) + ((r1[4] + r1[5]) + (r1[6] + r1[7]));
    anorm[m] = s0 + s1;
}

// ---------------- kernel 2: GEMM (sequential-k f32 FMA, BLAS order) + argmin --------
// Each block: BM=128 rows x one N-quarter (4096 cols). TM=8 x TN=16 per thread.
// d(m,n) = fl( fl(A_m + B_n) - 2*P_mn ); per-quarter lexicographic (d,n) top-1.
// lds_pad inflates static LDS to 56 KB -> backend occupancy bound = 2 blocks/CU
// = 2 waves/SIMD -> VGPR budget 256 -> acc[8][16] stays in registers (no spill).
__global__ __launch_bounds__(256, 2)
void k_argmin(const float* __restrict__ z,
              const float* __restrict__ cb,
              const float* __restrict__ cnorm,
              const float* __restrict__ anorm,
              float* __restrict__ pv,
              int* __restrict__ pi) {
    __shared__ float lds_a[2][BK][BM];   // 8 KB
    __shared__ float lds_b[2][BK][CT];   // 16 KB
    __shared__ char  lds_pad[32768];     // occupancy limiter (unused data)

    const int t  = threadIdx.x;
    if (t == 0) lds_pad[0] = 1;          // keep lds_pad allocated
    const int tx = t & 15;               // 16 col-groups
    const int ty = t >> 4;               // 16 row-groups (TM=8 rows each)
    const int mb   = (int)(blockIdx.x >> 2) * BM;
    const int quar = (int)(blockIdx.x & 3);
    const int colbase = quar * NQ;
    const int zb  = mb / HW;             // 128 | 1024: no batch straddle
    const int hw0 = mb % HW;
    const float* zbase = z + (size_t)zb * (CH * HW) + hw0;

    // staging roles
    const int sa_d = t >> 5;             // 0..7
    const int sa_m = (t & 31) * 4;       // 0..124

    float Am[8];
    #pragma unroll
    for (int i = 0; i < 8; ++i) Am[i] = anorm[mb + ty * 8 + i];

    float bv[8];
    int   bi[8];
    #pragma unroll
    for (int i = 0; i < 8; ++i) { bv[i] = INFINITY; bi[i] = 0x7fffffff; }

    for (int nt = 0; nt < NQ / CT; ++nt) {
        const int n0 = colbase + nt * CT;
        const float* crow = cb + (size_t)(n0 + t) * DIM;

        float acc[8][16];
        #pragma unroll
        for (int i = 0; i < 8; ++i)
            #pragma unroll
            for (int j = 0; j < 16; ++j) acc[i][j] = 0.f;

        // prologue: chunk 0 into buf 0
        float4 a0 = *reinterpret_cast<const float4*>(zbase + (size_t)sa_d * HW + sa_m);
        float4 u0 = *reinterpret_cast<const float4*>(crow + 0);
        float4 u1 = *reinterpret_cast<const float4*>(crow + 4);
        __syncthreads();  // previous tile's buffer reads complete
        *reinterpret_cast<float4*>(&lds_a[0][sa_d][sa_m]) = a0;
        lds_b[0][0][t] = u0.x; lds_b[0][1][t] = u0.y; lds_b[0][2][t] = u0.z; lds_b[0][3][t] = u0.w;
        lds_b[0][4][t] = u1.x; lds_b[0][5][t] = u1.y; lds_b[0][6][t] = u1.z; lds_b[0][7][t] = u1.w;

        for (int kc = 0; kc < DIM / BK; ++kc) {
            const int cur = kc & 1;
            __syncthreads();  // buf[cur] visible; buf[cur^1] free to overwrite

            float4 na, nb0, nb1;
            if (kc < DIM / BK - 1) {
                na  = *reinterpret_cast<const float4*>(zbase + (size_t)((kc + 1) * BK + sa_d) * HW + sa_m);
                nb0 = *reinterpret_cast<const float4*>(crow + (kc + 1) * BK);
                nb1 = *reinterpret_cast<const float4*>(crow + (kc + 1) * BK + 4);
            }

            #pragma unroll
            for (int kk = 0; kk < BK; ++kk) {
                float af[8];
                *reinterpret_cast<float4*>(&af[0]) = *reinterpret_cast<const float4*>(&lds_a[cur][kk][ty * 8]);
                *reinterpret_cast<float4*>(&af[4]) = *reinterpret_cast<const float4*>(&lds_a[cur][kk][ty * 8 + 4]);
                float bf[16];
                *reinterpret_cast<float4*>(&bf[0])  = *reinterpret_cast<const float4*>(&lds_b[cur][kk][tx * 4]);
                *reinterpret_cast<float4*>(&bf[4])  = *reinterpret_cast<const float4*>(&lds_b[cur][kk][64 + tx * 4]);
                *reinterpret_cast<float4*>(&bf[8])  = *reinterpret_cast<const float4*>(&lds_b[cur][kk][128 + tx * 4]);
                *reinterpret_cast<float4*>(&bf[12]) = *reinterpret_cast<const float4*>(&lds_b[cur][kk][192 + tx * 4]);
                #pragma unroll
                for (int i = 0; i < 8; ++i)
                    #pragma unroll
                    for (int j = 0; j < 16; ++j)
                        acc[i][j] = fmaf(af[i], bf[j], acc[i][j]);  // sequential k: matches sgemm
            }

            if (kc < DIM / BK - 1) {
                const int nb = cur ^ 1;
                *reinterpret_cast<float4*>(&lds_a[nb][sa_d][sa_m]) = na;
                lds_b[nb][0][t] = nb0.x; lds_b[nb][1][t] = nb0.y; lds_b[nb][2][t] = nb0.z; lds_b[nb][3][t] = nb0.w;
                lds_b[nb][4][t] = nb1.x; lds_b[nb][5][t] = nb1.y; lds_b[nb][6][t] = nb1.z; lds_b[nb][7][t] = nb1.w;
            }
        }

        // epilogue: d = fl(fl(Am+Bn) - 2*P); lexicographic (d, n) running min
        float cnv[16];
        #pragma unroll
        for (int jb = 0; jb < 4; ++jb) {
            float4 c4 = *reinterpret_cast<const float4*>(cnorm + n0 + jb * 64 + tx * 4);
            cnv[jb * 4 + 0] = c4.x; cnv[jb * 4 + 1] = c4.y;
            cnv[jb * 4 + 2] = c4.z; cnv[jb * 4 + 3] = c4.w;
        }
        #pragma unroll
        for (int i = 0; i < 8; ++i)
            #pragma unroll
            for (int jb = 0; jb < 4; ++jb)
                #pragma unroll
                for (int jj = 0; jj < 4; ++jj) {
                    float t1 = Am[i] + cnv[jb * 4 + jj];
                    float dd = t1 - 2.0f * acc[i][jb * 4 + jj];
                    int n = n0 + jb * 64 + tx * 4 + jj;
                    if (dd < bv[i] || (dd == bv[i] && n < bi[i])) { bv[i] = dd; bi[i] = n; }
                }
    }

    // reduce across the 16 tx lanes (lane bits 0..3: stays within wave & ty group)
    #pragma unroll
    for (int i = 0; i < 8; ++i) {
        #pragma unroll
        for (int o = 1; o < 16; o <<= 1) {
            float ov = __shfl_xor(bv[i], o, 64);
            int   oi = __shfl_xor(bi[i], o, 64);
            if (ov < bv[i] || (ov == bv[i] && oi < bi[i])) { bv[i] = ov; bi[i] = oi; }
        }
        if (tx == 0) {
            int row = mb + ty * 8 + i;
            pv[quar * MTOT + row] = bv[i];
            pi[quar * MTOT + row] = bi[i];
        }
    }
}

// ---------------- kernel 2b: combine the four N-quarters ----------------
__global__ __launch_bounds__(256) void k_combine(const float* __restrict__ pv,
                                                 const int* __restrict__ pi,
                                                 int* __restrict__ idxi,
                                                 float* __restrict__ idxf) {
    int m = blockIdx.x * 256 + threadIdx.x;
    float v = pv[m];
    int   i = pi[m];
    #pragma unroll
    for (int q = 1; q < 4; ++q) {
        float vq = pv[q * MTOT + m];
        int   iq = pi[q * MTOT + m];
        if (vq < v || (vq == v && iq < i)) { v = vq; i = iq; }
    }
    idxi[m] = i;
    idxf[m] = (float)i;
}

// ---------------- kernel 3: gather z_q, write out, accumulate loss ----------------
__global__ __launch_bounds__(256) void k_gather(const float* __restrict__ z,
                                                const float* __restrict__ cb,
                                                const int* __restrict__ idx,
                                                float* __restrict__ out,
                                                double* __restrict__ lacc) {
    int t = threadIdx.x;
    int hwi = t & 63, cg = t >> 6;
    int m = blockIdx.x * 64 + hwi;
    int b = m / HW, hw = m % HW;
    const float* erow = cb + (size_t)idx[m] * DIM;
    size_t zoff = (size_t)b * (CH * HW) + hw;
    double ls = 0.0;
    #pragma unroll 4
    for (int cc = 0; cc < 64; ++cc) {
        int c = cg * 64 + cc;
        float e  = erow[c];
        float zv = z[zoff + (size_t)c * HW];
        out[zoff + (size_t)c * HW] = e;
        float d = e - zv;
        ls += (double)d * (double)d;
    }
    #pragma unroll
    for (int o = 32; o; o >>= 1) ls += __shfl_xor(ls, o, 64);
    __shared__ double wsum[4];
    if ((t & 63) == 0) wsum[t >> 6] = ls;
    __syncthreads();
    if (t == 0) atomicAdd(lacc, wsum[0] + wsum[1] + wsum[2] + wsum[3]);
}

__global__ void k_final(const double* __restrict__ lacc, float* __restrict__ loss) {
    *loss = (float)(*lacc * (1.25 / (double)OUT_ELEMS));
}

extern "C" void kernel_launch(void* const* d_in, const int* in_sizes, int n_in,
                              void* d_out, int out_size, void* d_ws, size_t ws_size,
                              hipStream_t stream) {
    const float* z  = (const float*)d_in[0];
    const float* cb = (const float*)d_in[1];
    float* out      = (float*)d_out;
    float* loss_out = out + OUT_ELEMS;
    float* idxf     = out + OUT_ELEMS + 1;

    float*  cnorm = (float*)d_ws;                                  // 64 KB
    float*  anorm = (float*)((char*)d_ws + 65536);                 // 64 KB
    int*    idxi  = (int*)((char*)d_ws + 131072);                  // 64 KB
    float*  pv    = (float*)((char*)d_ws + 196608);                // 256 KB
    int*    pi    = (int*)((char*)d_ws + 458752);                  // 256 KB
    double* lacc  = (double*)((char*)d_ws + 720896);               // 8 B

    hipMemsetAsync(lacc, 0, sizeof(double), stream);

    k_cnorm  <<<NCODES / 256,    256, 0, stream>>>(cb, cnorm);
    k_anorm  <<<MTOT / 256,      256, 0, stream>>>(z, anorm);
    k_argmin <<<(MTOT / BM) * 4, 256, 0, stream>>>(z, cb, cnorm, anorm, pv, pi);
    k_combine<<<MTOT / 256,      256, 0, stream>>>(pv, pi, idxi, idxf);
    k_gather <<<MTOT / 64,       256, 0, stream>>>(z, cb, idxi, out, lacc);
    k_final  <<<1, 1, 0, stream>>>(lacc, loss_out);
}